// Round 7
// baseline (672.662 us; speedup 1.0000x reference)
//
#include <hip/hip_runtime.h>

// Shapes (fixed): B=2 S=2048 D=1024 R=64 N=16 H=16 DH=64
#define BS   4096
#define DD   1024
#define SEQ  2048
#define SLAB (BS * DD)          // 4,194,304 elems
#define POOL (16 * 64 * 1024)   // 1,048,576 elems per expert pool

typedef unsigned short u16;
typedef __attribute__((ext_vector_type(8))) short  s16x8;   // 8 bf16 MFMA frag
typedef __attribute__((ext_vector_type(4))) float  f32x4;   // MFMA accumulator

// ---- bf16 split helpers ---------------------------------------------------
__device__ __forceinline__ u16 f2bf(float x) {
    unsigned u = __float_as_uint(x);
    return (u16)((u + 0x7fffu + ((u >> 16) & 1u)) >> 16);   // RN-even
}
__device__ __forceinline__ float bf2f(u16 h) { return __uint_as_float(((unsigned)h) << 16); }
__device__ __forceinline__ void bsplit(float x, u16& h, u16& l) {
    h = f2bf(x);
    l = f2bf(x - bf2f(h));
}

// ---------------------------------------------------------------------------
// Elementwise fp32 -> (hi,lo) bf16. For x and W_O.
// ---------------------------------------------------------------------------
__global__ __launch_bounds__(256) void convert_ew(
    const float* __restrict__ in, u16* __restrict__ oh, u16* __restrict__ ol, int n4)
{
    for (int i = blockIdx.x * 256 + threadIdx.x; i < n4; i += gridDim.x * 256) {
        float4 v = ((const float4*)in)[i];
        u16 h0,h1,h2,h3, l0,l1,l2,l3;
        bsplit(v.x,h0,l0); bsplit(v.y,h1,l1); bsplit(v.z,h2,l2); bsplit(v.w,h3,l3);
        u16* ph = oh + i * 4; ph[0]=h0; ph[1]=h1; ph[2]=h2; ph[3]=h3;
        u16* pl = ol + i * 4; pl[0]=l0; pl[1]=l1; pl[2]=l2; pl[3]=l3;
    }
}

// ---------------------------------------------------------------------------
// Transposing convert for 3 pools of one kind:
//  f pools: input [d=1024][r=64] per expert, zPerPool=16 -> fT[n][r][d]
//  r pools: input [nr=1024][d=1024],        zPerPool=1  -> rT[d][nr]
// ---------------------------------------------------------------------------
__global__ __launch_bounds__(256) void convert_tr3(
    const float* __restrict__ in0, const float* __restrict__ in1, const float* __restrict__ in2,
    u16* __restrict__ oh, u16* __restrict__ ol, int Rows, int Cols, int zPerPool)
{
    __shared__ float ts[64][65];
    const int z = blockIdx.z, pool = z / zPerPool, zi = z % zPerPool;
    const float* in = (pool == 0 ? in0 : (pool == 1 ? in1 : in2)) + (size_t)zi * Rows * Cols;
    const size_t obase = (size_t)z * Rows * Cols;
    const int r0 = blockIdx.x * 64, c0 = blockIdx.y * 64;
    const int t = threadIdx.x;

    const int rr = t >> 4, c4 = (t & 15) * 4;
    #pragma unroll
    for (int i = 0; i < 4; ++i) {
        int r = i * 16 + rr;
        float4 v = *(const float4*)&in[(size_t)(r0 + r) * Cols + c0 + c4];
        ts[r][c4+0] = v.x; ts[r][c4+1] = v.y; ts[r][c4+2] = v.z; ts[r][c4+3] = v.w;
    }
    __syncthreads();
    const int cc = t >> 4, rq = (t & 15) * 4;
    #pragma unroll
    for (int i = 0; i < 4; ++i) {
        int c = i * 16 + cc;
        size_t o = obase + (size_t)(c0 + c) * Rows + r0 + rq;
        #pragma unroll
        for (int j = 0; j < 4; ++j) {
            u16 h, l; bsplit(ts[rq + j][c], h, l);
            oh[o + j] = h; ol[o + j] = l;
        }
    }
}

// ---------------------------------------------------------------------------
// Split-bf16 MFMA GEMM. C = A * Bt^T. Tile 128x128, K-step 32, 4 waves 2x2,
// wave tile 64x64 = 4x4 frags 16x16x32. 3-term split (AhBh+AhBl+AlBh).
// A-frags direct from global; B staged via global_load_lds.
// OMODE 0: fp32 C.  OMODE 1: split h/l C; if (vtrans && z==2) the output is
// written TRANSPOSED per head into Vt[bh][d][s] (same slab base) — feeds the
// de-staged attention's PV B-frags directly.
// ---------------------------------------------------------------------------
template<int OMODE>
__global__ __launch_bounds__(256, 3) void gemm_split(
    const u16* __restrict__ Ah, const u16* __restrict__ Al,
    const u16* __restrict__ Bh, const u16* __restrict__ Bl,
    float* __restrict__ Cf, u16* __restrict__ Ch, u16* __restrict__ Cl,
    long aZ, long bZ, long cZ, int K, int lda, int ldb, int ldc, int vtrans)
{
    __shared__ u16 sBh[128][32], sBl[128][32];

    const int t = threadIdx.x, wave = t >> 6, lane = t & 63;
    const int m0 = blockIdx.x * 128, n0 = blockIdx.y * 128;
    const long z = blockIdx.z;
    Ah += z * aZ; Al += z * aZ; Bh += z * bZ; Bl += z * bZ;

    // B staging: lane l covers row (l>>2) of a 16-row chunk, 16B segment (l&3)
    const int lr = lane >> 2, lk = (lane & 3) * 8;
    const u16* gBh = Bh + (size_t)(n0 + wave * 16 + lr) * ldb + lk;
    const u16* gBl = Bl + (size_t)(n0 + wave * 16 + lr) * ldb + lk;

    const int fr = lane & 15, fk = (lane >> 4) * 8;
    // A direct: lane owns row m0+(wave>>1)*64+16i+fr, k-seg fk (16B aligned)
    const u16* gAh = Ah + (size_t)(m0 + (wave >> 1) * 64 + fr) * lda + fk;
    const u16* gAl = Al + (size_t)(m0 + (wave >> 1) * 64 + fr) * lda + fk;

    f32x4 acc[4][4];
    #pragma unroll
    for (int i = 0; i < 4; ++i)
        #pragma unroll
        for (int j = 0; j < 4; ++j) acc[i][j] = (f32x4){0.f, 0.f, 0.f, 0.f};

    const int br = (wave & 1) * 64 + fr;

    for (int k0 = 0; k0 < K; k0 += 32) {
        // stage B h/l (each wave: chunks {wave, wave+4})
        #define STG(g, s, ld) do { \
            __builtin_amdgcn_global_load_lds( \
                (const __attribute__((address_space(1))) void*)(g + k0), \
                (__attribute__((address_space(3))) void*)&s[wave * 16][0], 16, 0, 0); \
            __builtin_amdgcn_global_load_lds( \
                (const __attribute__((address_space(1))) void*)(g + k0 + (size_t)64 * ld), \
                (__attribute__((address_space(3))) void*)&s[wave * 16 + 64][0], 16, 0, 0); \
        } while (0)
        STG(gBh, sBh, ldb); STG(gBl, sBl, ldb);
        #undef STG

        // A frags direct from global — overlap the B DMA, drained by barrier
        s16x8 ahf[4], alf[4];
        #pragma unroll
        for (int i = 0; i < 4; ++i) {
            ahf[i] = *(const s16x8*)&gAh[(size_t)(16 * i) * lda + k0];
            alf[i] = *(const s16x8*)&gAl[(size_t)(16 * i) * lda + k0];
        }
        __syncthreads();

        #pragma unroll
        for (int j = 0; j < 4; ++j) {
            s16x8 bh = *(const s16x8*)&sBh[br + 16 * j][fk];
            s16x8 bl = *(const s16x8*)&sBl[br + 16 * j][fk];
            #pragma unroll
            for (int i = 0; i < 4; ++i)
                acc[i][j] = __builtin_amdgcn_mfma_f32_16x16x32_bf16(ahf[i], bh, acc[i][j], 0, 0, 0);
            #pragma unroll
            for (int i = 0; i < 4; ++i)
                acc[i][j] = __builtin_amdgcn_mfma_f32_16x16x32_bf16(ahf[i], bl, acc[i][j], 0, 0, 0);
            #pragma unroll
            for (int i = 0; i < 4; ++i)
                acc[i][j] = __builtin_amdgcn_mfma_f32_16x16x32_bf16(alf[i], bh, acc[i][j], 0, 0, 0);
        }
        __syncthreads();
    }

    // epilogue — C/D map: col = lane&15, row = (lane>>4)*4 + reg  [m89]
    const int row0 = m0 + (wave >> 1) * 64 + (lane >> 4) * 4;
    const int col0 = n0 + (wave & 1) * 64 + fr;
    if constexpr (OMODE == 0) {
        Cf += z * cZ;
        #pragma unroll
        for (int i = 0; i < 4; ++i)
            #pragma unroll
            for (int j = 0; j < 4; ++j)
                #pragma unroll
                for (int r = 0; r < 4; ++r)
                    Cf[(size_t)(row0 + 16 * i + r) * ldc + col0 + 16 * j] = acc[i][j][r];
    } else {
        Ch += z * cZ; Cl += z * cZ;
        if (vtrans && z == 2) {
            // V projection: write Vt[bh][d][s] (s contiguous = acc reg dim)
            const int b_ = m0 >> 11;
            const int h_ = (n0 + (wave & 1) * 64) >> 6;
            #pragma unroll
            for (int i = 0; i < 4; ++i) {
                int srow = (m0 & (SEQ - 1)) + (wave >> 1) * 64 + (lane >> 4) * 4 + 16 * i;
                #pragma unroll
                for (int j = 0; j < 4; ++j) {
                    int d = fr + 16 * j;
                    size_t o = ((size_t)((b_ * 16 + h_) * 64 + d)) * SEQ + srow;
                    ushort4 hv, lv;
                    bsplit(acc[i][j][0], hv.x, lv.x);
                    bsplit(acc[i][j][1], hv.y, lv.y);
                    bsplit(acc[i][j][2], hv.z, lv.z);
                    bsplit(acc[i][j][3], hv.w, lv.w);
                    *(ushort4*)&Ch[o] = hv;
                    *(ushort4*)&Cl[o] = lv;
                }
            }
        } else {
            #pragma unroll
            for (int i = 0; i < 4; ++i)
                #pragma unroll
                for (int j = 0; j < 4; ++j)
                    #pragma unroll
                    for (int r = 0; r < 4; ++r) {
                        u16 h, l; bsplit(acc[i][j][r], h, l);
                        size_t o = (size_t)(row0 + 16 * i + r) * ldc + col0 + 16 * j;
                        Ch[o] = h; Cl[o] = l;
                    }
        }
    }
}

// ---------------------------------------------------------------------------
// mix (batched over 3 projections), in place on split-bf16 T.
// ---------------------------------------------------------------------------
__global__ __launch_bounds__(256) void mix3(
    u16* __restrict__ Th, u16* __restrict__ Tl,
    const float* fw0, const float* fw1, const float* fw2,
    const float* rw0, const float* rw1, const float* rw2)
{
    const int p = blockIdx.y;
    const float* fw = p == 0 ? fw0 : (p == 1 ? fw1 : fw2);
    const float* rw = p == 0 ? rw0 : (p == 1 ? rw1 : rw2);
    u16* th = Th + (size_t)p * SLAB;
    u16* tl = Tl + (size_t)p * SLAB;

    const int t = threadIdx.x;
    const int bs = blockIdx.x * 4 + (t >> 6);
    const int r = t & 63;
    const float* fwp = fw + bs * 16;
    const float* rwp = rw + bs * 16;
    u16* rowh = th + (size_t)bs * DD + r;
    u16* rowl = tl + (size_t)bs * DD + r;

    float h = 0.f;
    #pragma unroll
    for (int n = 0; n < 16; ++n) h += fwp[n] * (bf2f(rowh[n * 64]) + bf2f(rowl[n * 64]));
    #pragma unroll
    for (int n = 0; n < 16; ++n) {
        u16 hh, ll; bsplit(rwp[n] * h, hh, ll);
        rowh[n * 64] = hh; rowl[n * 64] = ll;
    }
}

// ---------------------------------------------------------------------------
// Split-bf16 MFMA causal flash attention — DE-STAGED (r6 rocprof-driven):
// the r6 kernel spent ~100+ us on scalar LDS transpose/staging stores
// (MfmaUtil 10%, 1.6e7 bank conflicts). Now K and V^T fragments are loaded
// DIRECT from global (K natural layout; V^T produced by the restore GEMM),
// data identical to what the LDS path delivered. No barriers remain — only
// the wave-private swizzled P round-trip stays in LDS (32 KB).
// Grid remap unchanged: pairs (bx, 15-bx) per CU.
// ---------------------------------------------------------------------------
__global__ __launch_bounds__(256) void attn_mfma(
    const u16* __restrict__ Qh, const u16* __restrict__ Ql,
    const u16* __restrict__ Kh, const u16* __restrict__ Kl,
    const u16* __restrict__ Vth, const u16* __restrict__ Vtl,
    u16* __restrict__ Oh, u16* __restrict__ Ol)
{
    __shared__ u16 sPh[128][64], sPl[128][64];   // [qrow][k], XOR-swizzled

    const int t = threadIdx.x, w = t >> 6, lane = t & 63;
    const int g = blockIdx.x;
    const int u = g & 255, v = g >> 8;
    const int bh = (v << 4) + (u >> 4);          // b*16 + h
    const int bx = v ? (15 - (u & 15)) : (u & 15);
    const int b = bh >> 4, h = bh & 15;
    const int q0 = bx * 128;
    const int l15 = lane & 15, l4 = lane >> 4;

    // Q fragments (A operand): row = l15, k = l4*8+j
    s16x8 qfh[2][2], qfl[2][2];
    #pragma unroll
    for (int fi = 0; fi < 2; ++fi) {
        int qr = q0 + w * 32 + fi * 16 + l15;
        size_t base = ((size_t)(b * SEQ + qr)) * DD + h * 64;
        #pragma unroll
        for (int dk = 0; dk < 2; ++dk) {
            qfh[fi][dk] = *(const s16x8*)&Qh[base + dk * 32 + l4 * 8];
            qfl[fi][dk] = *(const s16x8*)&Ql[base + dk * 32 + l4 * 8];
        }
    }

    f32x4 oacc[2][4];
    #pragma unroll
    for (int fi = 0; fi < 2; ++fi)
        #pragma unroll
        for (int dj = 0; dj < 4; ++dj) oacc[fi][dj] = (f32x4){0.f,0.f,0.f,0.f};
    float mrow[2][4], lrow[2][4];
    #pragma unroll
    for (int fi = 0; fi < 2; ++fi)
        #pragma unroll
        for (int r = 0; r < 4; ++r) { mrow[fi][r] = -1e30f; lrow[fi][r] = 0.f; }

    const int ntiles = 2 * bx + 2;
    for (int kt = 0; kt < ntiles; ++kt) {
        // ---- QK^T (3-term split), B-frags direct from global K ----
        f32x4 s[2][4];
        #pragma unroll
        for (int fi = 0; fi < 2; ++fi)
            #pragma unroll
            for (int fj = 0; fj < 4; ++fj) s[fi][fj] = (f32x4){0.f,0.f,0.f,0.f};
        #pragma unroll
        for (int fj = 0; fj < 4; ++fj) {
            size_t kbase = ((size_t)(b * SEQ + kt * 64 + fj * 16 + l15)) * DD + h * 64;
            #pragma unroll
            for (int dk = 0; dk < 2; ++dk) {
                s16x8 kbh = *(const s16x8*)&Kh[kbase + dk * 32 + l4 * 8];
                s16x8 kbl = *(const s16x8*)&Kl[kbase + dk * 32 + l4 * 8];
                #pragma unroll
                for (int fi = 0; fi < 2; ++fi) {
                    s[fi][fj] = __builtin_amdgcn_mfma_f32_16x16x32_bf16(qfh[fi][dk], kbh, s[fi][fj], 0,0,0);
                    s[fi][fj] = __builtin_amdgcn_mfma_f32_16x16x32_bf16(qfh[fi][dk], kbl, s[fi][fj], 0,0,0);
                    s[fi][fj] = __builtin_amdgcn_mfma_f32_16x16x32_bf16(qfl[fi][dk], kbh, s[fi][fj], 0,0,0);
                }
            }
        }

        // ---- scale + causal mask (C/D: row=(l>>4)*4+r, col=l15) ----
        #pragma unroll
        for (int fi = 0; fi < 2; ++fi) {
            int qrow = q0 + w * 32 + fi * 16 + l4 * 4;
            #pragma unroll
            for (int fj = 0; fj < 4; ++fj) {
                int kcol = kt * 64 + fj * 16 + l15;
                #pragma unroll
                for (int r = 0; r < 4; ++r)
                    s[fi][fj][r] = (kcol > qrow + r) ? -1e9f : s[fi][fj][r] * 0.125f;
            }
        }

        // ---- online softmax (row-reduce = 16-lane butterfly) ----
        #pragma unroll
        for (int fi = 0; fi < 2; ++fi) {
            f32x4 pm = s[fi][0];
            #pragma unroll
            for (int fj = 1; fj < 4; ++fj)
                #pragma unroll
                for (int r = 0; r < 4; ++r) pm[r] = fmaxf(pm[r], s[fi][fj][r]);
            #pragma unroll
            for (int st = 1; st < 16; st <<= 1)
                #pragma unroll
                for (int r = 0; r < 4; ++r) pm[r] = fmaxf(pm[r], __shfl_xor(pm[r], st));

            float al[4];
            #pragma unroll
            for (int r = 0; r < 4; ++r) {
                float mn = fmaxf(mrow[fi][r], pm[r]);
                al[r] = __expf(mrow[fi][r] - mn);
                mrow[fi][r] = mn;
            }
            f32x4 rs = (f32x4){0.f,0.f,0.f,0.f};
            #pragma unroll
            for (int fj = 0; fj < 4; ++fj) {
                #pragma unroll
                for (int r = 0; r < 4; ++r) {
                    float p = __expf(s[fi][fj][r] - mrow[fi][r]);
                    rs[r] += p;
                    u16 ph, pl; bsplit(p, ph, pl);
                    int prow = w * 32 + fi * 16 + l4 * 4 + r;
                    int byte = ((fj * 16 + l15) * 2) ^ ((prow & 7) << 4);
                    *(u16*)((char*)&sPh[prow][0] + byte) = ph;
                    *(u16*)((char*)&sPl[prow][0] + byte) = pl;
                }
            }
            #pragma unroll
            for (int st = 1; st < 16; st <<= 1)
                #pragma unroll
                for (int r = 0; r < 4; ++r) rs[r] += __shfl_xor(rs[r], st);
            #pragma unroll
            for (int r = 0; r < 4; ++r) {
                lrow[fi][r] = lrow[fi][r] * al[r] + rs[r];
                #pragma unroll
                for (int dj = 0; dj < 4; ++dj) oacc[fi][dj][r] *= al[r];
            }
        }
        // no barrier: P rows are wave-private; same-wave LDS order preserved.

        // ---- PV (3-term split), V^T frags direct from global Vt ----
        #pragma unroll
        for (int kk = 0; kk < 2; ++kk) {
            s16x8 pah[2], pal[2];
            #pragma unroll
            for (int fi = 0; fi < 2; ++fi) {
                int prow = w * 32 + fi * 16 + l15;
                int byte = ((kk * 32 + l4 * 8) * 2) ^ ((prow & 7) << 4);
                pah[fi] = *(const s16x8*)((const char*)&sPh[prow][0] + byte);
                pal[fi] = *(const s16x8*)((const char*)&sPl[prow][0] + byte);
            }
            #pragma unroll
            for (int dj = 0; dj < 4; ++dj) {
                size_t vbase = ((size_t)(bh * 64 + dj * 16 + l15)) * SEQ + kt * 64 + kk * 32 + l4 * 8;
                s16x8 vbh = *(const s16x8*)&Vth[vbase];
                s16x8 vbl = *(const s16x8*)&Vtl[vbase];
                #pragma unroll
                for (int fi = 0; fi < 2; ++fi) {
                    oacc[fi][dj] = __builtin_amdgcn_mfma_f32_16x16x32_bf16(pah[fi], vbh, oacc[fi][dj], 0,0,0);
                    oacc[fi][dj] = __builtin_amdgcn_mfma_f32_16x16x32_bf16(pah[fi], vbl, oacc[fi][dj], 0,0,0);
                    oacc[fi][dj] = __builtin_amdgcn_mfma_f32_16x16x32_bf16(pal[fi], vbh, oacc[fi][dj], 0,0,0);
                }
            }
        }
    }

    // ---- epilogue: O = acc / l, split h/l ----
    #pragma unroll
    for (int fi = 0; fi < 2; ++fi)
        #pragma unroll
        for (int r = 0; r < 4; ++r) {
            int qr = q0 + w * 32 + fi * 16 + l4 * 4 + r;
            size_t base = ((size_t)(b * SEQ + qr)) * DD + h * 64;
            float inv = 1.0f / lrow[fi][r];
            #pragma unroll
            for (int dj = 0; dj < 4; ++dj) {
                u16 hh, ll; bsplit(oacc[fi][dj][r] * inv, hh, ll);
                Oh[base + dj * 16 + l15] = hh;
                Ol[base + dj * 16 + l15] = ll;
            }
        }
}

// ---------------------------------------------------------------------------
extern "C" void kernel_launch(void* const* d_in, const int* in_sizes, int n_in,
                              void* d_out, int out_size, void* d_ws, size_t ws_size,
                              hipStream_t stream)
{
    const float* x     = (const float*)d_in[0];
    const float* fw[3] = { (const float*)d_in[1], (const float*)d_in[2], (const float*)d_in[3] };
    const float* rw[3] = { (const float*)d_in[4], (const float*)d_in[5], (const float*)d_in[6] };
    const float* fp[3] = { (const float*)d_in[7], (const float*)d_in[8], (const float*)d_in[9] };
    const float* rp[3] = { (const float*)d_in[10], (const float*)d_in[11], (const float*)d_in[12] };
    const float* Wo    = (const float*)d_in[13];
    float* out = (float*)d_out;

    // workspace (u16 elems), ~147 MB total (same as r6's passing layout)
    u16* U    = (u16*)d_ws;
    u16* xh   = U;                  u16* xl   = xh  + SLAB;      // dead after compress
    u16* fTh  = xl   + SLAB;        u16* fTl  = fTh + 3 * POOL;
    u16* rTh  = fTl  + 3 * POOL;    u16* rTl  = rTh + 3 * POOL;
    u16* Wh   = rTl  + 3 * POOL;    u16* Wl   = Wh  + POOL;
    u16* Th   = Wl   + POOL;        u16* Tl   = Th  + 3 * SLAB;
    u16* QKVh = Tl   + 3 * SLAB;    u16* QKVl = QKVh + 3 * SLAB;
    u16* Ohb  = xh;                 u16* Olb  = xl;              // attn out aliases x

    dim3 blk(256);

    // 1) conversions
    convert_ew<<<dim3(4096), blk, 0, stream>>>(x,  xh, xl, SLAB / 4);
    convert_ew<<<dim3(1024), blk, 0, stream>>>(Wo, Wh, Wl, (DD * DD) / 4);
    convert_tr3<<<dim3(16, 1, 48), blk, 0, stream>>>(fp[0], fp[1], fp[2], fTh, fTl, 1024, 64, 16);
    convert_tr3<<<dim3(16, 16, 3), blk, 0, stream>>>(rp[0], rp[1], rp[2], rTh, rTl, 1024, 1024, 1);

    // 2) compress x3 (z-batched): T[p] = x @ fT[p]^T  -> split bf16
    gemm_split<1><<<dim3(32, 8, 3), blk, 0, stream>>>(
        xh, xl, fTh, fTl, nullptr, Th, Tl, 0, POOL, SLAB, DD, DD, DD, DD, 0);

    // 3) mix x3 in place
    mix3<<<dim3(BS / 4, 3), blk, 0, stream>>>(
        Th, Tl, fw[0], fw[1], fw[2], rw[0], rw[1], rw[2]);

    // 4) restore x3 (z-batched): Q,K normal layout; V written TRANSPOSED
    //    into its slab (Vt[bh][d][s]) for the de-staged attention.
    gemm_split<1><<<dim3(32, 8, 3), blk, 0, stream>>>(
        Th, Tl, rTh, rTl, nullptr, QKVh, QKVl, SLAB, POOL, SLAB, DD, DD, DD, DD, 1);

    // 5) MFMA causal flash attention (no K/V staging, no barriers)
    attn_mfma<<<dim3(512), blk, 0, stream>>>(
        QKVh, QKVl, QKVh + SLAB, QKVl + SLAB, QKVh + 2 * SLAB, QKVl + 2 * SLAB,
        Ohb, Olb);

    // 6) out = O @ W_O^T -> fp32
    gemm_split<0><<<dim3(32, 8, 1), blk, 0, stream>>>(
        Ohb, Olb, Wh, Wl, out, nullptr, nullptr, 0, 0, 0, DD, DD, DD, DD, 0);
}

// Round 10
// 533.279 us; speedup vs baseline: 1.2614x; 1.2614x over previous
//
#include <hip/hip_runtime.h>

// Shapes (fixed): B=2 S=2048 D=1024 R=64 N=16 H=16 DH=64
#define BS   4096
#define DD   1024
#define SEQ  2048
#define SLAB (BS * DD)          // 4,194,304 elems
#define POOL (16 * 64 * 1024)   // 1,048,576 elems per expert pool

typedef unsigned short u16;
typedef __attribute__((ext_vector_type(8))) short  s16x8;   // 8 bf16 MFMA frag
typedef __attribute__((ext_vector_type(4))) float  f32x4;   // MFMA accumulator

// ---- bf16 split helpers ---------------------------------------------------
__device__ __forceinline__ u16 f2bf(float x) {
    unsigned u = __float_as_uint(x);
    return (u16)((u + 0x7fffu + ((u >> 16) & 1u)) >> 16);   // RN-even
}
__device__ __forceinline__ float bf2f(u16 h) { return __uint_as_float(((unsigned)h) << 16); }
__device__ __forceinline__ void bsplit(float x, u16& h, u16& l) {
    h = f2bf(x);
    l = f2bf(x - bf2f(h));
}

// ---------------------------------------------------------------------------
// Elementwise fp32 -> (hi,lo) bf16. For x and W_O.
// ---------------------------------------------------------------------------
__global__ __launch_bounds__(256) void convert_ew(
    const float* __restrict__ in, u16* __restrict__ oh, u16* __restrict__ ol, int n4)
{
    for (int i = blockIdx.x * 256 + threadIdx.x; i < n4; i += gridDim.x * 256) {
        float4 v = ((const float4*)in)[i];
        u16 h0,h1,h2,h3, l0,l1,l2,l3;
        bsplit(v.x,h0,l0); bsplit(v.y,h1,l1); bsplit(v.z,h2,l2); bsplit(v.w,h3,l3);
        u16* ph = oh + i * 4; ph[0]=h0; ph[1]=h1; ph[2]=h2; ph[3]=h3;
        u16* pl = ol + i * 4; pl[0]=l0; pl[1]=l1; pl[2]=l2; pl[3]=l3;
    }
}

// ---------------------------------------------------------------------------
// Transposing convert for 3 pools of one kind:
//  f pools: input [d=1024][r=64] per expert, zPerPool=16 -> fT[n][r][d]
//  r pools: input [nr=1024][d=1024],        zPerPool=1  -> rT[d][nr]
// ---------------------------------------------------------------------------
__global__ __launch_bounds__(256) void convert_tr3(
    const float* __restrict__ in0, const float* __restrict__ in1, const float* __restrict__ in2,
    u16* __restrict__ oh, u16* __restrict__ ol, int Rows, int Cols, int zPerPool)
{
    __shared__ float ts[64][65];
    const int z = blockIdx.z, pool = z / zPerPool, zi = z % zPerPool;
    const float* in = (pool == 0 ? in0 : (pool == 1 ? in1 : in2)) + (size_t)zi * Rows * Cols;
    const size_t obase = (size_t)z * Rows * Cols;
    const int r0 = blockIdx.x * 64, c0 = blockIdx.y * 64;
    const int t = threadIdx.x;

    const int rr = t >> 4, c4 = (t & 15) * 4;
    #pragma unroll
    for (int i = 0; i < 4; ++i) {
        int r = i * 16 + rr;
        float4 v = *(const float4*)&in[(size_t)(r0 + r) * Cols + c0 + c4];
        ts[r][c4+0] = v.x; ts[r][c4+1] = v.y; ts[r][c4+2] = v.z; ts[r][c4+3] = v.w;
    }
    __syncthreads();
    const int cc = t >> 4, rq = (t & 15) * 4;
    #pragma unroll
    for (int i = 0; i < 4; ++i) {
        int c = i * 16 + cc;
        size_t o = obase + (size_t)(c0 + c) * Rows + r0 + rq;
        #pragma unroll
        for (int j = 0; j < 4; ++j) {
            u16 h, l; bsplit(ts[rq + j][c], h, l);
            oh[o + j] = h; ol[o + j] = l;
        }
    }
}

// ---------------------------------------------------------------------------
// Split-bf16 MFMA GEMM (passed r6/r7). C = A * Bt^T.
// OMODE 0: fp32 C.  OMODE 1: split h/l C; if (vtrans && z==2) output written
// TRANSPOSED per head into Vt[bh][d][s].
// ---------------------------------------------------------------------------
template<int OMODE>
__global__ __launch_bounds__(256, 3) void gemm_split(
    const u16* __restrict__ Ah, const u16* __restrict__ Al,
    const u16* __restrict__ Bh, const u16* __restrict__ Bl,
    float* __restrict__ Cf, u16* __restrict__ Ch, u16* __restrict__ Cl,
    long aZ, long bZ, long cZ, int K, int lda, int ldb, int ldc, int vtrans)
{
    __shared__ u16 sBh[128][32], sBl[128][32];

    const int t = threadIdx.x, wave = t >> 6, lane = t & 63;
    const int m0 = blockIdx.x * 128, n0 = blockIdx.y * 128;
    const long z = blockIdx.z;
    Ah += z * aZ; Al += z * aZ; Bh += z * bZ; Bl += z * bZ;

    const int lr = lane >> 2, lk = (lane & 3) * 8;
    const u16* gBh = Bh + (size_t)(n0 + wave * 16 + lr) * ldb + lk;
    const u16* gBl = Bl + (size_t)(n0 + wave * 16 + lr) * ldb + lk;

    const int fr = lane & 15, fk = (lane >> 4) * 8;
    const u16* gAh = Ah + (size_t)(m0 + (wave >> 1) * 64 + fr) * lda + fk;
    const u16* gAl = Al + (size_t)(m0 + (wave >> 1) * 64 + fr) * lda + fk;

    f32x4 acc[4][4];
    #pragma unroll
    for (int i = 0; i < 4; ++i)
        #pragma unroll
        for (int j = 0; j < 4; ++j) acc[i][j] = (f32x4){0.f, 0.f, 0.f, 0.f};

    const int br = (wave & 1) * 64 + fr;

    for (int k0 = 0; k0 < K; k0 += 32) {
        #define STG(g, s, ld) do { \
            __builtin_amdgcn_global_load_lds( \
                (const __attribute__((address_space(1))) void*)(g + k0), \
                (__attribute__((address_space(3))) void*)&s[wave * 16][0], 16, 0, 0); \
            __builtin_amdgcn_global_load_lds( \
                (const __attribute__((address_space(1))) void*)(g + k0 + (size_t)64 * ld), \
                (__attribute__((address_space(3))) void*)&s[wave * 16 + 64][0], 16, 0, 0); \
        } while (0)
        STG(gBh, sBh, ldb); STG(gBl, sBl, ldb);
        #undef STG

        s16x8 ahf[4], alf[4];
        #pragma unroll
        for (int i = 0; i < 4; ++i) {
            ahf[i] = *(const s16x8*)&gAh[(size_t)(16 * i) * lda + k0];
            alf[i] = *(const s16x8*)&gAl[(size_t)(16 * i) * lda + k0];
        }
        __syncthreads();

        #pragma unroll
        for (int j = 0; j < 4; ++j) {
            s16x8 bh = *(const s16x8*)&sBh[br + 16 * j][fk];
            s16x8 bl = *(const s16x8*)&sBl[br + 16 * j][fk];
            #pragma unroll
            for (int i = 0; i < 4; ++i)
                acc[i][j] = __builtin_amdgcn_mfma_f32_16x16x32_bf16(ahf[i], bh, acc[i][j], 0, 0, 0);
            #pragma unroll
            for (int i = 0; i < 4; ++i)
                acc[i][j] = __builtin_amdgcn_mfma_f32_16x16x32_bf16(ahf[i], bl, acc[i][j], 0, 0, 0);
            #pragma unroll
            for (int i = 0; i < 4; ++i)
                acc[i][j] = __builtin_amdgcn_mfma_f32_16x16x32_bf16(alf[i], bh, acc[i][j], 0, 0, 0);
        }
        __syncthreads();
    }

    const int row0 = m0 + (wave >> 1) * 64 + (lane >> 4) * 4;
    const int col0 = n0 + (wave & 1) * 64 + fr;
    if constexpr (OMODE == 0) {
        Cf += z * cZ;
        #pragma unroll
        for (int i = 0; i < 4; ++i)
            #pragma unroll
            for (int j = 0; j < 4; ++j)
                #pragma unroll
                for (int r = 0; r < 4; ++r)
                    Cf[(size_t)(row0 + 16 * i + r) * ldc + col0 + 16 * j] = acc[i][j][r];
    } else {
        Ch += z * cZ; Cl += z * cZ;
        if (vtrans && z == 2) {
            const int b_ = m0 >> 11;
            const int h_ = (n0 + (wave & 1) * 64) >> 6;
            #pragma unroll
            for (int i = 0; i < 4; ++i) {
                int srow = (m0 & (SEQ - 1)) + (wave >> 1) * 64 + (lane >> 4) * 4 + 16 * i;
                #pragma unroll
                for (int j = 0; j < 4; ++j) {
                    int d = fr + 16 * j;
                    size_t o = ((size_t)((b_ * 16 + h_) * 64 + d)) * SEQ + srow;
                    ushort4 hv, lv;
                    bsplit(acc[i][j][0], hv.x, lv.x);
                    bsplit(acc[i][j][1], hv.y, lv.y);
                    bsplit(acc[i][j][2], hv.z, lv.z);
                    bsplit(acc[i][j][3], hv.w, lv.w);
                    *(ushort4*)&Ch[o] = hv;
                    *(ushort4*)&Cl[o] = lv;
                }
            }
        } else {
            #pragma unroll
            for (int i = 0; i < 4; ++i)
                #pragma unroll
                for (int j = 0; j < 4; ++j)
                    #pragma unroll
                    for (int r = 0; r < 4; ++r) {
                        u16 h, l; bsplit(acc[i][j][r], h, l);
                        size_t o = (size_t)(row0 + 16 * i + r) * ldc + col0 + 16 * j;
                        Ch[o] = h; Cl[o] = l;
                    }
        }
    }
}

// ---------------------------------------------------------------------------
// mix (batched over 3 projections), in place on split-bf16 T.
// ---------------------------------------------------------------------------
__global__ __launch_bounds__(256) void mix3(
    u16* __restrict__ Th, u16* __restrict__ Tl,
    const float* fw0, const float* fw1, const float* fw2,
    const float* rw0, const float* rw1, const float* rw2)
{
    const int p = blockIdx.y;
    const float* fw = p == 0 ? fw0 : (p == 1 ? fw1 : fw2);
    const float* rw = p == 0 ? rw0 : (p == 1 ? rw1 : rw2);
    u16* th = Th + (size_t)p * SLAB;
    u16* tl = Tl + (size_t)p * SLAB;

    const int t = threadIdx.x;
    const int bs = blockIdx.x * 4 + (t >> 6);
    const int r = t & 63;
    const float* fwp = fw + bs * 16;
    const float* rwp = rw + bs * 16;
    u16* rowh = th + (size_t)bs * DD + r;
    u16* rowl = tl + (size_t)bs * DD + r;

    float h = 0.f;
    #pragma unroll
    for (int n = 0; n < 16; ++n) h += fwp[n] * (bf2f(rowh[n * 64]) + bf2f(rowl[n * 64]));
    #pragma unroll
    for (int n = 0; n < 16; ++n) {
        u16 hh, ll; bsplit(rwp[n] * h, hh, ll);
        rowh[n * 64] = hh; rowl[n * 64] = ll;
    }
}

// ---------------------------------------------------------------------------
// Split-bf16 MFMA causal flash attention (r8 design, audits r9/r10):
//  - QBLK=64, 4 waves x 16 q-rows -> grid 1024, LDS 48KB -> 3 blocks/CU;
//    bx = 31-(g>>5) = longest-first (LPT) scheduling.
//  - K and Vt staged via global_load_lds w16 with PRE-SWIZZLED global source
//    (linear LDS dest; chunk c -> row=c>>3, seg=(c&7)^(row&7)); frag reads
//    use the verified XOR involution -> conflict-free, zero scalar stores.
//  - P round-trip wave-private (no barrier).
// ---------------------------------------------------------------------------
__global__ __launch_bounds__(256, 3) void attn_mfma(
    const u16* __restrict__ Qh, const u16* __restrict__ Ql,
    const u16* __restrict__ Kh, const u16* __restrict__ Kl,
    const u16* __restrict__ Vth, const u16* __restrict__ Vtl,
    u16* __restrict__ Oh, u16* __restrict__ Ol)
{
    __shared__ u16 sKh[64][64], sKl[64][64];   // [krow][d], XOR-swizzled
    __shared__ u16 sVh[64][64], sVl[64][64];   // [d][k],    XOR-swizzled
    __shared__ u16 sPh[64][64], sPl[64][64];   // [qrow][k], XOR-swizzled

    const int t = threadIdx.x, w = t >> 6, lane = t & 63;
    const int g = blockIdx.x;
    const int bh = g & 31;                     // b*16 + h
    const int bx = 31 - (g >> 5);              // LPT: big causal tiles first
    const int b = bh >> 4, h = bh & 15;
    const int q0 = bx * 64;
    const int l15 = lane & 15, l4 = lane >> 4;

    const u16* Kbh = Kh  + ((size_t)b * SEQ) * DD + h * 64;
    const u16* Kbl = Kl  + ((size_t)b * SEQ) * DD + h * 64;
    const u16* Vbh = Vth + ((size_t)bh * 64) * SEQ;
    const u16* Vbl = Vtl + ((size_t)bh * 64) * SEQ;

    // Q frags: 16 q-rows/wave; A-frag row = l15, k = dk*32 + l4*8 + j
    s16x8 qfh[2], qfl[2];
    {
        int qr = q0 + w * 16 + l15;
        size_t base = ((size_t)(b * SEQ + qr)) * DD + h * 64;
        #pragma unroll
        for (int dk = 0; dk < 2; ++dk) {
            qfh[dk] = *(const s16x8*)&Qh[base + dk * 32 + l4 * 8];
            qfl[dk] = *(const s16x8*)&Ql[base + dk * 32 + l4 * 8];
        }
    }

    f32x4 oacc[4];
    #pragma unroll
    for (int dj = 0; dj < 4; ++dj) oacc[dj] = (f32x4){0.f,0.f,0.f,0.f};
    float mrow[4], lrow[4];
    #pragma unroll
    for (int r = 0; r < 4; ++r) { mrow[r] = -1e30f; lrow[r] = 0.f; }

    const int ntiles = bx + 1;
    for (int kt = 0; kt < ntiles; ++kt) {
        __syncthreads();   // prev-tile readers done before DMA restage
        // ---- stage K h/l and Vt h/l: 512 chunks of 16B per buffer;
        //      linear LDS dest, pre-swizzled global source ----
        #pragma unroll
        for (int i = 0; i < 2; ++i) {
            int c   = i * 256 + t;             // chunk id = wave-uniform base + lane
            int row = c >> 3;
            int seg = (c & 7) ^ (row & 7);
            int ldsoff = (i * 256 + w * 64) * 8;   // u16 elems, wave-uniform
            const u16* gkh = Kbh + (size_t)(kt * 64 + row) * DD + seg * 8;
            const u16* gkl = Kbl + (size_t)(kt * 64 + row) * DD + seg * 8;
            const u16* gvh = Vbh + (size_t)row * SEQ + kt * 64 + seg * 8;
            const u16* gvl = Vbl + (size_t)row * SEQ + kt * 64 + seg * 8;
            __builtin_amdgcn_global_load_lds((const __attribute__((address_space(1))) void*)gkh,
                (__attribute__((address_space(3))) void*)(&sKh[0][0] + ldsoff), 16, 0, 0);
            __builtin_amdgcn_global_load_lds((const __attribute__((address_space(1))) void*)gkl,
                (__attribute__((address_space(3))) void*)(&sKl[0][0] + ldsoff), 16, 0, 0);
            __builtin_amdgcn_global_load_lds((const __attribute__((address_space(1))) void*)gvh,
                (__attribute__((address_space(3))) void*)(&sVh[0][0] + ldsoff), 16, 0, 0);
            __builtin_amdgcn_global_load_lds((const __attribute__((address_space(1))) void*)gvl,
                (__attribute__((address_space(3))) void*)(&sVl[0][0] + ldsoff), 16, 0, 0);
        }
        __syncthreads();   // barrier drains vmcnt -> tiles ready

        // ---- QK^T (3-term split) ----
        f32x4 s[4];
        #pragma unroll
        for (int fj = 0; fj < 4; ++fj) s[fj] = (f32x4){0.f,0.f,0.f,0.f};
        #pragma unroll
        for (int fj = 0; fj < 4; ++fj) {
            int krow = fj * 16 + l15;
            #pragma unroll
            for (int dk = 0; dk < 2; ++dk) {
                int byte = ((dk * 32 + l4 * 8) * 2) ^ ((krow & 7) << 4);
                s16x8 kbh = *(const s16x8*)((const char*)&sKh[krow][0] + byte);
                s16x8 kbl = *(const s16x8*)((const char*)&sKl[krow][0] + byte);
                s[fj] = __builtin_amdgcn_mfma_f32_16x16x32_bf16(qfh[dk], kbh, s[fj], 0,0,0);
                s[fj] = __builtin_amdgcn_mfma_f32_16x16x32_bf16(qfh[dk], kbl, s[fj], 0,0,0);
                s[fj] = __builtin_amdgcn_mfma_f32_16x16x32_bf16(qfl[dk], kbh, s[fj], 0,0,0);
            }
        }

        // ---- scale + causal mask (C/D: row=(l>>4)*4+r, col=l15) ----
        {
            int qrow = q0 + w * 16 + l4 * 4;
            #pragma unroll
            for (int fj = 0; fj < 4; ++fj) {
                int kcol = kt * 64 + fj * 16 + l15;
                #pragma unroll
                for (int r = 0; r < 4; ++r)
                    s[fj][r] = (kcol > qrow + r) ? -1e9f : s[fj][r] * 0.125f;
            }
        }

        // ---- online softmax (row-reduce = 16-lane butterfly) ----
        {
            f32x4 pm = s[0];
            #pragma unroll
            for (int fj = 1; fj < 4; ++fj)
                #pragma unroll
                for (int r = 0; r < 4; ++r) pm[r] = fmaxf(pm[r], s[fj][r]);
            #pragma unroll
            for (int st = 1; st < 16; st <<= 1)
                #pragma unroll
                for (int r = 0; r < 4; ++r) pm[r] = fmaxf(pm[r], __shfl_xor(pm[r], st));

            float al[4];
            #pragma unroll
            for (int r = 0; r < 4; ++r) {
                float mn = fmaxf(mrow[r], pm[r]);
                al[r] = __expf(mrow[r] - mn);
                mrow[r] = mn;
            }
            f32x4 rs = (f32x4){0.f,0.f,0.f,0.f};
            #pragma unroll
            for (int fj = 0; fj < 4; ++fj) {
                #pragma unroll
                for (int r = 0; r < 4; ++r) {
                    float p = __expf(s[fj][r] - mrow[r]);
                    rs[r] += p;
                    u16 ph, pl; bsplit(p, ph, pl);
                    int prow = w * 16 + l4 * 4 + r;
                    int byte = ((fj * 16 + l15) * 2) ^ ((prow & 7) << 4);
                    *(u16*)((char*)&sPh[prow][0] + byte) = ph;
                    *(u16*)((char*)&sPl[prow][0] + byte) = pl;
                }
            }
            #pragma unroll
            for (int st = 1; st < 16; st <<= 1)
                #pragma unroll
                for (int r = 0; r < 4; ++r) rs[r] += __shfl_xor(rs[r], st);
            #pragma unroll
            for (int r = 0; r < 4; ++r) {
                lrow[r] = lrow[r] * al[r] + rs[r];
                #pragma unroll
                for (int dj = 0; dj < 4; ++dj) oacc[dj][r] *= al[r];
            }
        }
        // no barrier: P rows wave-private; same-wave LDS order preserved.

        // ---- PV (3-term split) ----
        #pragma unroll
        for (int kk = 0; kk < 2; ++kk) {
            int prow = w * 16 + l15;
            int pbyte = ((kk * 32 + l4 * 8) * 2) ^ ((prow & 7) << 4);
            s16x8 pah = *(const s16x8*)((const char*)&sPh[prow][0] + pbyte);
            s16x8 pal = *(const s16x8*)((const char*)&sPl[prow][0] + pbyte);
            #pragma unroll
            for (int dj = 0; dj < 4; ++dj) {
                int vrow = dj * 16 + l15;
                int vbyte = ((kk * 32 + l4 * 8) * 2) ^ ((vrow & 7) << 4);
                s16x8 vbh = *(const s16x8*)((const char*)&sVh[vrow][0] + vbyte);
                s16x8 vbl = *(const s16x8*)((const char*)&sVl[vrow][0] + vbyte);
                oacc[dj] = __builtin_amdgcn_mfma_f32_16x16x32_bf16(pah, vbh, oacc[dj], 0,0,0);
                oacc[dj] = __builtin_amdgcn_mfma_f32_16x16x32_bf16(pah, vbl, oacc[dj], 0,0,0);
                oacc[dj] = __builtin_amdgcn_mfma_f32_16x16x32_bf16(pal, vbh, oacc[dj], 0,0,0);
            }
        }
    }

    // ---- epilogue: O = acc / l, split h/l ----
    #pragma unroll
    for (int r = 0; r < 4; ++r) {
        int qr = q0 + w * 16 + l4 * 4 + r;
        size_t base = ((size_t)(b * SEQ + qr)) * DD + h * 64;
        float inv = 1.0f / lrow[r];
        #pragma unroll
        for (int dj = 0; dj < 4; ++dj) {
            u16 hh, ll; bsplit(oacc[dj][r] * inv, hh, ll);
            Oh[base + dj * 16 + l15] = hh;
            Ol[base + dj * 16 + l15] = ll;
        }
    }
}

// ---------------------------------------------------------------------------
extern "C" void kernel_launch(void* const* d_in, const int* in_sizes, int n_in,
                              void* d_out, int out_size, void* d_ws, size_t ws_size,
                              hipStream_t stream)
{
    const float* x     = (const float*)d_in[0];
    const float* fw[3] = { (const float*)d_in[1], (const float*)d_in[2], (const float*)d_in[3] };
    const float* rw[3] = { (const float*)d_in[4], (const float*)d_in[5], (const float*)d_in[6] };
    const float* fp[3] = { (const float*)d_in[7], (const float*)d_in[8], (const float*)d_in[9] };
    const float* rp[3] = { (const float*)d_in[10], (const float*)d_in[11], (const float*)d_in[12] };
    const float* Wo    = (const float*)d_in[13];
    float* out = (float*)d_out;

    // workspace (u16 elems), ~147 MB total
    u16* U    = (u16*)d_ws;
    u16* xh   = U;                  u16* xl   = xh  + SLAB;      // dead after compress
    u16* fTh  = xl   + SLAB;        u16* fTl  = fTh + 3 * POOL;
    u16* rTh  = fTl  + 3 * POOL;    u16* rTl  = rTh + 3 * POOL;
    u16* Wh   = rTl  + 3 * POOL;    u16* Wl   = Wh  + POOL;
    u16* Th   = Wl   + POOL;        u16* Tl   = Th  + 3 * SLAB;
    u16* QKVh = Tl   + 3 * SLAB;    u16* QKVl = QKVh + 3 * SLAB;
    u16* Ohb  = xh;                 u16* Olb  = xl;              // attn out aliases x

    dim3 blk(256);

    // 1) conversions
    convert_ew<<<dim3(4096), blk, 0, stream>>>(x,  xh, xl, SLAB / 4);
    convert_ew<<<dim3(1024), blk, 0, stream>>>(Wo, Wh, Wl, (DD * DD) / 4);
    convert_tr3<<<dim3(16, 1, 48), blk, 0, stream>>>(fp[0], fp[1], fp[2], fTh, fTl, 1024, 64, 16);
    convert_tr3<<<dim3(16, 16, 3), blk, 0, stream>>>(rp[0], rp[1], rp[2], rTh, rTl, 1024, 1024, 1);

    // 2) compress x3 (z-batched): T[p] = x @ fT[p]^T  -> split bf16
    gemm_split<1><<<dim3(32, 8, 3), blk, 0, stream>>>(
        xh, xl, fTh, fTl, nullptr, Th, Tl, 0, POOL, SLAB, DD, DD, DD, DD, 0);

    // 3) mix x3 in place
    mix3<<<dim3(BS / 4, 3), blk, 0, stream>>>(
        Th, Tl, fw[0], fw[1], fw[2], rw[0], rw[1], rw[2]);

    // 4) restore x3 (z-batched): Q,K normal layout; V written TRANSPOSED
    gemm_split<1><<<dim3(32, 8, 3), blk, 0, stream>>>(
        Th, Tl, rTh, rTl, nullptr, QKVh, QKVl, SLAB, POOL, SLAB, DD, DD, DD, DD, 1);

    // 5) MFMA causal flash attention (DMA-staged K/Vt, QBLK=64, LPT grid)
    attn_mfma<<<dim3(1024), blk, 0, stream>>>(
        QKVh, QKVl, QKVh + SLAB, QKVl + SLAB, QKVh + 2 * SLAB, QKVl + 2 * SLAB,
        Ohb, Olb);

    // 6) out = O @ W_O^T -> fp32
    gemm_split<0><<<dim3(32, 8, 1), blk, 0, stream>>>(
        Ohb, Olb, Wh, Wl, out, nullptr, nullptr, 0, 0, 0, DD, DD, DD, DD, 0);
}